// Round 9
// baseline (16984.903 us; speedup 1.0000x reference)
//
#include <hip/hip_runtime.h>
#include <hip/hip_bf16.h>
#include <hip/hip_fp16.h>

#define BB  512
#define TT  256
#define MM  81
#define HEE 256

// ---- workspace layout (float offsets) ----
#define OFF_W2AH   0          // half2[256 k2][256 j]  encoder p1 weight pairs
#define OFF_WE8    65536      // uint4[169 k2][256 j]  encoder LSTM, gate-major pairs
#define OFF_W4D1   238592     // uint2[128 k4][256 j]  decoder p1 pairs
#define OFF_WD8    304128     // uint4[128 k2][256 j]  decoder Whh, gate-major pairs
#define OFF_ATTN   436224     // [512][81] attn_in
#define OFF_ENCW   477696     // [512][256] enc . W_fc[:256]
#define OFF_ENC    608768     // [512][256][256] input_encoded fp32
#define OFF_EPI    34163200   // half[512 b][256 t'][256 h] enc_proj
#define WS_FLOATS  50940416

typedef _Float16 hh2 __attribute__((ext_vector_type(2)));

__device__ __forceinline__ float frcp(float x) { return __builtin_amdgcn_rcpf(x); }
__device__ __forceinline__ float fsig(float x) { return frcp(1.f + __expf(-x)); }
__device__ __forceinline__ float ftanh(float x) { return 1.f - 2.f * frcp(__expf(2.f * x) + 1.f); }
__device__ __forceinline__ hh2 uash2(unsigned int u) { union { unsigned int u; hh2 h; } x; x.u = u; return x.h; }
__device__ __forceinline__ float fdot2f(unsigned int a, unsigned int b, float c) {
#if __has_builtin(__builtin_amdgcn_fdot2)
  return __builtin_amdgcn_fdot2(uash2(a), uash2(b), c, false);
#else
  hh2 ha = uash2(a), hb = uash2(b);
  return c + (float)ha.x * (float)hb.x + (float)ha.y * (float)hb.y;
#endif
}
__device__ __forceinline__ ushort f2h(float x) { return __half_as_ushort(__float2half(x)); }

// AGPR stash: volatile write pins the value in an AGPR (allocator-visible via "a").
#define AGW(var, x) asm volatile("v_accvgpr_write_b32 %0, %1" : "=a"(var) : "v"(x))
#define AGR(x, var) asm("v_accvgpr_read_b32 %0, %1" : "=v"(x) : "a"(var))

// ---------------- weight prep ----------------
__global__ void k_prep(const float* __restrict__ W_ah, const float* __restrict__ Wih_e,
                       const float* __restrict__ Whh_e, const float* __restrict__ W_d1,
                       const float* __restrict__ Wih_d, const float* __restrict__ Whh_d,
                       float* __restrict__ ws) {
  int idx = blockIdx.x * 512 + threadIdx.x;
  if (idx < 65536) {  // encoder p1 pairs
    int k2 = idx >> 8, j = idx & 255;
    ((__half2*)(ws + OFF_W2AH))[idx] =
        __floats2half2_rn(W_ah[j * 512 + 2 * k2], W_ah[j * 512 + 2 * k2 + 1]);
  }
  if (idx < 32768) {  // decoder p1 pairs
    int k4 = idx >> 8, j = idx & 255;
    __half2 a = __floats2half2_rn(W_d1[j * 768 + 4 * k4 + 0], W_d1[j * 768 + 4 * k4 + 1]);
    __half2 b = __floats2half2_rn(W_d1[j * 768 + 4 * k4 + 2], W_d1[j * 768 + 4 * k4 + 3]);
    uint2 w;
    w.x = *(const unsigned int*)&a;
    w.y = *(const unsigned int*)&b;
    ((uint2*)(ws + OFF_W4D1))[idx] = w;
  }
  if (idx < 43264) {  // encoder LSTM: gate-major pairs over u=[wi(81);h(256);pad]
    int k2 = idx >> 8, j = idx & 255;
    auto we = [&](int g, int kk) -> float {
      if (kk < 81)  return Wih_e[(g * 256 + j) * 81 + kk];
      if (kk < 337) return Whh_e[(g * 256 + j) * 256 + (kk - 81)];
      return 0.f;
    };
    int ke = 2 * k2, ko = 2 * k2 + 1;
    union { __half2 h[4]; uint4 u; } w;
    w.h[0] = __floats2half2_rn(we(0, ke), we(0, ko));
    w.h[1] = __floats2half2_rn(we(1, ke), we(1, ko));
    w.h[2] = __floats2half2_rn(we(2, ke), we(2, ko));
    w.h[3] = __floats2half2_rn(we(3, ke), we(3, ko));
    ((uint4*)(ws + OFF_WE8))[idx] = w.u;
  }
  if (idx < 32768) {  // decoder Whh: gate-major pairs, 128 k2
    int k2 = idx >> 8, j = idx & 255;
    int ke = 2 * k2, ko = 2 * k2 + 1;
    union { __half2 h[4]; uint4 u; } w;
    w.h[0] = __floats2half2_rn(Whh_d[(0 * 256 + j) * 256 + ke], Whh_d[(0 * 256 + j) * 256 + ko]);
    w.h[1] = __floats2half2_rn(Whh_d[(1 * 256 + j) * 256 + ke], Whh_d[(1 * 256 + j) * 256 + ko]);
    w.h[2] = __floats2half2_rn(Whh_d[(2 * 256 + j) * 256 + ke], Whh_d[(2 * 256 + j) * 256 + ko]);
    w.h[3] = __floats2half2_rn(Whh_d[(3 * 256 + j) * 256 + ke], Whh_d[(3 * 256 + j) * 256 + ko]);
    ((uint4*)(ws + OFF_WD8))[idx] = w.u;
  }
}

// ---------------- attn_in[b][m] ----------------
__global__ void k_attn(const float* __restrict__ x, const float* __restrict__ W_ai,
                       const float* __restrict__ b_ai, float* __restrict__ ws) {
  __shared__ float wai[256];
  const int b = blockIdx.x, tid = threadIdx.x;  // 128 threads
  wai[tid] = W_ai[tid];
  wai[128 + tid] = W_ai[128 + tid];
  __syncthreads();
  if (tid < MM) {
    float acc = b_ai[0];
    const float* xp = x + (size_t)b * TT * MM + tid;
    #pragma unroll 8
    for (int t = 0; t < TT; ++t) acc = fmaf(xp[t * MM], wai[t], acc);
    ws[OFF_ATTN + b * MM + tid] = acc;
  }
}

// ---------------- encoder: unchanged from R8 ----------------
__global__ __launch_bounds__(1024, 2) void k_encoder(
    const float* __restrict__ x, const float* __restrict__ b_ah,
    const float* __restrict__ W_a, const float* __restrict__ b_a,
    const float* __restrict__ bih_e, const float* __restrict__ bhh_e,
    float* __restrict__ ws) {
  __shared__ __align__(16) float aA[2048];
  __shared__ __align__(16) float4 gA[2048];
  __shared__ __align__(16) float hpb[512];
  __shared__ __align__(16) float wa2[256];
  __shared__ __align__(16) ushort hcb[2][512];
  __shared__ __align__(16) ushort uu[2][344];
  const int tid = threadIdx.x;
  const int j = tid & 255, q = tid >> 8;
  const int b0 = blockIdx.x * 2, b1 = b0 + 1;

  if (tid < 256) wa2[tid] = W_a[tid];
  if (tid < 512) { hcb[0][tid] = 0; hcb[1][tid] = 0; }
  if (tid < 344) { uu[0][tid] = 0; uu[1][tid] = 0; }
  float bahr = 0.f; float4 bias4 = {0, 0, 0, 0};
  if (tid < 512) {
    bahr = b_ah[j];
    bias4.x = bih_e[j] + bhh_e[j];
    bias4.y = bih_e[256 + j] + bhh_e[256 + j];
    bias4.z = bih_e[512 + j] + bhh_e[512 + j];
    bias4.w = bih_e[768 + j] + bhh_e[768 + j];
  }
  float ai0 = 0.f, ai1 = 0.f;
  {
    int m = tid & 127;
    if (m < MM) {
      ai0 = ws[OFF_ATTN + b0 * MM + m];
      ai1 = ws[OFF_ATTN + b1 * MM + m];
    }
  }
  const float bav = b_a[0];
  float xc0 = 0.f, xc1 = 0.f;
  if (tid < 128) {
    int bb = (tid >= 64) ? b1 : b0;
    int lane = tid & 63;
    xc0 = x[((size_t)bb * TT) * MM + lane];
    xc1 = (lane < 17) ? x[((size_t)bb * TT) * MM + 64 + lane] : 0.f;
  }
  const unsigned int* __restrict__ Wah2u = (const unsigned int*)(ws + OFF_W2AH);
  const uint4* __restrict__ We8 = (const uint4*)(ws + OFF_WE8);
  const unsigned int* __restrict__ hc0 = (const unsigned int*)hcb[0];
  const unsigned int* __restrict__ hc1 = (const unsigned int*)hcb[1];
  const unsigned int* __restrict__ u0p = (const unsigned int*)uu[0];
  const unsigned int* __restrict__ u1p = (const unsigned int*)uu[1];
  float creg = 0.f;
  __syncthreads();

  for (int t = 0; t < TT; ++t) {
    {
      float a0 = 0.f, a1 = 0.f;
      const int kb = q * 64;
      #pragma unroll 8
      for (int i = 0; i < 64; ++i) {
        unsigned int w = Wah2u[(kb + i) * 256 + j];
        a0 = fdot2f(w, hc0[kb + i], a0);
        a1 = fdot2f(w, hc1[kb + i], a1);
      }
      aA[(q * 256 + j) * 2 + 0] = a0;
      aA[(q * 256 + j) * 2 + 1] = a1;
      float4 g0 = {0, 0, 0, 0}, g1 = {0, 0, 0, 0};
      const int ku0 = 41 + q * 32;
      #pragma unroll 4
      for (int i = 0; i < 32; ++i) {
        int ku = ku0 + i;
        uint4 wu = We8[ku * 256 + j];
        unsigned int ua = u0p[ku], ub = u1p[ku];
        g0.x = fdot2f(wu.x, ua, g0.x); g0.y = fdot2f(wu.y, ua, g0.y);
        g0.z = fdot2f(wu.z, ua, g0.z); g0.w = fdot2f(wu.w, ua, g0.w);
        g1.x = fdot2f(wu.x, ub, g1.x); g1.y = fdot2f(wu.y, ub, g1.y);
        g1.z = fdot2f(wu.z, ub, g1.z); g1.w = fdot2f(wu.w, ub, g1.w);
      }
      gA[(q * 2 + 0) * 256 + j] = g0;
      gA[(q * 2 + 1) * 256 + j] = g1;
    }
    __syncthreads();
    if (tid < 512) {
      int b = tid >> 8, h = tid & 255;
      hpb[2 * h + b] = aA[(0 * 256 + h) * 2 + b] + aA[(1 * 256 + h) * 2 + b] +
                       aA[(2 * 256 + h) * 2 + b] + aA[(3 * 256 + h) * 2 + b] + bahr;
    }
    __syncthreads();
    {
      int m = tid & 127, tq = tid >> 7;
      if (m < MM) {
        float e0 = 0.f, e1 = 0.f;
        #pragma unroll 8
        for (int i = tq * 16; i < tq * 16 + 16; ++i) {
          float4 hv = *(const float4*)&hpb[i * 4];
          float2 wv = *(const float2*)&wa2[i * 2];
          e0 += ftanh(hv.x + ai0) * wv.x + ftanh(hv.z + ai0) * wv.y;
          e1 += ftanh(hv.y + ai1) * wv.x + ftanh(hv.w + ai1) * wv.y;
        }
        aA[(tq * 2 + 0) * 96 + m] = e0;
        aA[(tq * 2 + 1) * 96 + m] = e1;
      }
    }
    __syncthreads();
    if (tid < 128) {
      int wv_id = tid >> 6, lane = tid & 63;
      float v0 = bav, v1 = bav;
      #pragma unroll
      for (int tq = 0; tq < 8; ++tq) {
        v0 += aA[(tq * 2 + wv_id) * 96 + lane];
        if (lane < 17) v1 += aA[(tq * 2 + wv_id) * 96 + 64 + lane];
      }
      float e0 = __expf(v0);
      float e1 = (lane < 17) ? __expf(v1) : 0.f;
      float sm = e0 + e1;
      #pragma unroll
      for (int d = 1; d < 64; d <<= 1) sm += __shfl_xor(sm, d);
      float inv = frcp(sm);
      uu[wv_id][lane] = f2h(e0 * inv * xc0);
      if (lane < 17) uu[wv_id][64 + lane] = f2h(e1 * inv * xc1);
      if (t < 255) {
        int bb = wv_id ? b1 : b0;
        xc0 = x[((size_t)bb * TT + t + 1) * MM + lane];
        xc1 = (lane < 17) ? x[((size_t)bb * TT + t + 1) * MM + 64 + lane] : 0.f;
      }
    }
    __syncthreads();
    {
      const int kA = (q == 0) ? 0 : (q == 1) ? 11 : (q == 2) ? 21 : 31;
      const int kB = (q == 0) ? 11 : (q == 1) ? 21 : (q == 2) ? 31 : 41;
      float4 g0 = gA[(q * 2 + 0) * 256 + j];
      float4 g1 = gA[(q * 2 + 1) * 256 + j];
      for (int ku = kA; ku < kB; ++ku) {
        uint4 wu = We8[ku * 256 + j];
        unsigned int ua = u0p[ku], ub = u1p[ku];
        g0.x = fdot2f(wu.x, ua, g0.x); g0.y = fdot2f(wu.y, ua, g0.y);
        g0.z = fdot2f(wu.z, ua, g0.z); g0.w = fdot2f(wu.w, ua, g0.w);
        g1.x = fdot2f(wu.x, ub, g1.x); g1.y = fdot2f(wu.y, ub, g1.y);
        g1.z = fdot2f(wu.z, ub, g1.z); g1.w = fdot2f(wu.w, ub, g1.w);
      }
      gA[(q * 2 + 0) * 256 + j] = g0;
      gA[(q * 2 + 1) * 256 + j] = g1;
    }
    __syncthreads();
    if (tid < 512) {
      int b = tid >> 8, jj = tid & 255;
      float4 s0 = gA[(0 * 2 + b) * 256 + jj];
      float4 s1 = gA[(1 * 2 + b) * 256 + jj];
      float4 s2 = gA[(2 * 2 + b) * 256 + jj];
      float4 s3 = gA[(3 * 2 + b) * 256 + jj];
      float gi = s0.x + s1.x + s2.x + s3.x + bias4.x;
      float gf = s0.y + s1.y + s2.y + s3.y + bias4.y;
      float gg = s0.z + s1.z + s2.z + s3.z + bias4.z;
      float go = s0.w + s1.w + s2.w + s3.w + bias4.w;
      float c = fsig(gf) * creg + fsig(gi) * ftanh(gg);
      float h = fsig(go) * ftanh(c);
      creg = c;
      hcb[b][jj] = f2h(h);
      hcb[b][256 + jj] = f2h(c);
      uu[b][81 + jj] = f2h(h);
      ws[OFF_ENC + (((size_t)(b ? b1 : b0) * TT + t) * HEE + jj)] = h;
    }
    __syncthreads();
  }
}

// ---------------- encW[b][t] = enc[b,t,:] . W_fc[:256] ----------------
__global__ __launch_bounds__(256) void k_encw(const float* __restrict__ W_fc, float* __restrict__ ws) {
  const float* __restrict__ enc = ws + OFF_ENC;
  const int wv = threadIdx.x >> 6, lane = threadIdx.x & 63;
  float4 wfc = reinterpret_cast<const float4*>(W_fc)[lane];
  for (int r = blockIdx.x * 4 + wv; r < BB * TT; r += 4096) {
    float4 e = reinterpret_cast<const float4*>(enc + (size_t)r * HEE)[lane];
    float d = e.x * wfc.x + e.y * wfc.y + e.z * wfc.z + e.w * wfc.w;
    #pragma unroll
    for (int dd = 1; dd < 64; dd <<= 1) d += __shfl_xor(d, dd);
    if (lane == 0) ws[OFF_ENCW + r] = d;
  }
}

// ---------------- enc_proj fp16: epH[b][t'][h] ----------------
__global__ __launch_bounds__(256) void k_encproj(const float* __restrict__ W_d1, float* __restrict__ ws) {
  __shared__ __align__(16) float le[16][256];
  const int tid = threadIdx.x;
  const int b = blockIdx.x >> 4;
  const int t0 = (blockIdx.x & 15) * 16;
  const float* __restrict__ enc = ws + OFF_ENC;
  __half* __restrict__ epH = (__half*)(ws + OFF_EPI);
  #pragma unroll
  for (int rr = 0; rr < 16; ++rr)
    le[rr][tid] = enc[((size_t)b * TT + (t0 + rr)) * HEE + tid];
  __syncthreads();
  const float4* wrow = (const float4*)(W_d1 + (size_t)tid * 768 + 512);
  float acc[16];
  #pragma unroll
  for (int r = 0; r < 16; ++r) acc[r] = 0.f;
  for (int e4 = 0; e4 < 64; ++e4) {
    float4 w = wrow[e4];
    #pragma unroll
    for (int r = 0; r < 16; ++r) {
      float4 ev = *(const float4*)&le[r][e4 * 4];
      acc[r] += ev.x * w.x + ev.y * w.y + ev.z * w.z + ev.w * w.w;
    }
  }
  #pragma unroll
  for (int rr = 0; rr < 16; ++rr)
    epH[((size_t)b * TT + (t0 + rr)) * HEE + tid] = __float2half(acc[rr]);
}

// ---------------- decoder: 1024 threads, 2 batches per step (b1 ep in AGPRs), 255 steps ----------------
__global__ __launch_bounds__(1024) void k_decoder(
    const float* __restrict__ y_history, const float* __restrict__ b_d1,
    const float* __restrict__ W_d2, const float* __restrict__ b_d2,
    const float* __restrict__ W_fc, const float* __restrict__ b_fc,
    const float* __restrict__ Wih_d,
    const float* __restrict__ bih_d, const float* __restrict__ bhh_d,
    const float* __restrict__ W_ff, const float* __restrict__ b_ff,
    float* __restrict__ ws, float* __restrict__ out) {
  __shared__ __align__(16) ushort epL[65536];   // b0 enc_proj, swizzled, 128 KB
  __shared__ __align__(16) float aA[2048];      // matvec / score / ctx partials (x2 batches)
  __shared__ __align__(16) float4 gA4[1024];    // gate partials (q=(b,half)), 16 KB; aliased as awls in finale
  __shared__ __align__(16) ushort hcb[2][512];  // fp16 [h;c] per batch
  __shared__ __align__(16) float ddp2[512];     // d packed 2h+b
  __shared__ __align__(16) float w2f[256];      // W_d2 fp32
  __shared__ __align__(16) float ybuf[512];     // y*wfcy+bfc, 2s+b
  __shared__ float red[2][8];
  const int tid = threadIdx.x;
  const int tp = tid & 255, q = tid >> 8;
  const int lane = tid & 63, wvid = tid >> 6;
  const int b0 = blockIdx.x * 2, b1 = b0 + 1;
  const float wfcy = W_fc[256], bfc = b_fc[0], bd2v = b_d2[0], bffv = b_ff[0];

  if (tid < 256) w2f[tid] = W_d2[tid];
  ((ushort*)hcb)[tid] = 0;
  if (tid < 510) {
    int s = tid >> 1, b = tid & 1;
    ybuf[tid] = y_history[(size_t)(b ? b1 : b0) * 255 + s] * wfcy + bfc;
  }
  const float bd1r = b_d1[tp];
  float4 biasd, wy;
  biasd.x = bih_d[tp] + bhh_d[tp];
  biasd.y = bih_d[256 + tp] + bhh_d[256 + tp];
  biasd.z = bih_d[512 + tp] + bhh_d[512 + tp];
  biasd.w = bih_d[768 + tp] + bhh_d[768 + tp];
  wy.x = Wih_d[tp]; wy.y = Wih_d[256 + tp]; wy.z = Wih_d[512 + tp]; wy.w = Wih_d[768 + tp];
  const float wffh = W_ff[tp], wffc = W_ff[256 + tp];
  const float ewr = (q < 2) ? ws[OFF_ENCW + (size_t)(q ? b1 : b0) * 256 + tp] : 0.f;

  const uint2* __restrict__ W4 = (const uint2*)(ws + OFF_W4D1);
  const uint4* __restrict__ Wd8 = (const uint4*)(ws + OFF_WD8);
  const uint4* __restrict__ epg = (const uint4*)(ws + OFF_EPI);
  const uint4* __restrict__ ep16 = (const uint4*)epL;
  const unsigned int* __restrict__ hc0u = (const unsigned int*)hcb[0];
  const unsigned int* __restrict__ hc1u = (const unsigned int*)hcb[1];

  // ---- b0 enc_proj -> swizzled LDS ----
  {
    const uint4* src = epg + (size_t)b0 * 8192;
    #pragma unroll
    for (int k = 0; k < 8; ++k) {
      int g = k * 1024 + tid;
      int t = g >> 5, c = g & 31;
      ((uint4*)epL)[(g & ~31) | (c ^ (t & 31))] = src[g];
    }
  }
  // ---- b1 enc_proj slice -> 32 AGPRs ----
  unsigned ag00, ag01, ag02, ag03, ag04, ag05, ag06, ag07,
           ag08, ag09, ag10, ag11, ag12, ag13, ag14, ag15,
           ag16, ag17, ag18, ag19, ag20, ag21, ag22, ag23,
           ag24, ag25, ag26, ag27, ag28, ag29, ag30, ag31;
  {
    const uint4* s1 = epg + (size_t)b1 * 8192 + tp * 32 + q * 8;
    uint4 t;
    t = s1[0]; AGW(ag00, t.x); AGW(ag01, t.y); AGW(ag02, t.z); AGW(ag03, t.w);
    t = s1[1]; AGW(ag04, t.x); AGW(ag05, t.y); AGW(ag06, t.z); AGW(ag07, t.w);
    t = s1[2]; AGW(ag08, t.x); AGW(ag09, t.y); AGW(ag10, t.z); AGW(ag11, t.w);
    t = s1[3]; AGW(ag12, t.x); AGW(ag13, t.y); AGW(ag14, t.z); AGW(ag15, t.w);
    t = s1[4]; AGW(ag16, t.x); AGW(ag17, t.y); AGW(ag18, t.z); AGW(ag19, t.w);
    t = s1[5]; AGW(ag20, t.x); AGW(ag21, t.y); AGW(ag22, t.z); AGW(ag23, t.w);
    t = s1[6]; AGW(ag24, t.x); AGW(ag25, t.y); AGW(ag26, t.z); AGW(ag27, t.w);
    t = s1[7]; AGW(ag28, t.x); AGW(ag29, t.y); AGW(ag30, t.z); AGW(ag31, t.w);
  }
  __syncthreads();

  float hreg = 0.f, creg = 0.f;   // fp32 master state for tid<512 (b = tid>>8)
  float esc = 0.f, invls = 0.f;   // last-step softmax pieces (q<2)

#define CSTEP(K, A0, A1, A2, A3)                                                \
  {                                                                             \
    uint4 e0u = ep16[rowbase + ((q * 8 + (K)) ^ sw)];                           \
    unsigned r0, r1, r2, r3;                                                    \
    AGR(r0, A0); AGR(r1, A1); AGR(r2, A2); AGR(r3, A3);                         \
    const int h8 = q * 64 + (K) * 8;                                            \
    const __half2* e0h = (const __half2*)&e0u;                                  \
    const unsigned rr[4] = {r0, r1, r2, r3};                                    \
    _Pragma("unroll")                                                           \
    for (int jj = 0; jj < 4; ++jj) {                                            \
      float2 ea = __half22float2(e0h[jj]);                                      \
      __half2 hb = *(__half2*)&rr[jj];                                          \
      float2 eb = __half22float2(hb);                                           \
      float2 wf = *(const float2*)&w2f[h8 + 2 * jj];                            \
      float4 dv = *(const float4*)&ddp2[2 * (h8 + 2 * jj)];                     \
      q0 += wf.x * ftanh(ea.x + dv.x) + wf.y * ftanh(ea.y + dv.z);              \
      q1 += wf.x * ftanh(eb.x + dv.y) + wf.y * ftanh(eb.y + dv.w);              \
    }                                                                           \
  }

  for (int s = 0; s < 255; ++s) {
    // ---- A: p1 partials (both batches, shared weight loads) + Whh gate partials ----
    {
      float a0 = 0.f, a1 = 0.f;
      const int k4b = q * 32;
      #pragma unroll 8
      for (int i = 0; i < 32; ++i) {
        int k4 = k4b + i;
        uint2 wu = W4[k4 * 256 + tp];
        a0 = fdot2f(wu.x, hc0u[2 * k4], a0);
        a0 = fdot2f(wu.y, hc0u[2 * k4 + 1], a0);
        a1 = fdot2f(wu.x, hc1u[2 * k4], a1);
        a1 = fdot2f(wu.y, hc1u[2 * k4 + 1], a1);
      }
      aA[(q * 256 + tp) * 2 + 0] = a0;
      aA[(q * 256 + tp) * 2 + 1] = a1;
      const int gb = q >> 1, gh = q & 1;
      const unsigned int* hcu = gb ? hc1u : hc0u;
      float4 g = {0, 0, 0, 0};
      const int kA = gh * 64;
      #pragma unroll 4
      for (int k2 = kA; k2 < kA + 64; ++k2) {
        uint4 wu = Wd8[k2 * 256 + tp];
        unsigned int u2 = hcu[k2];
        g.x = fdot2f(wu.x, u2, g.x); g.y = fdot2f(wu.y, u2, g.y);
        g.z = fdot2f(wu.z, u2, g.z); g.w = fdot2f(wu.w, u2, g.w);
      }
      gA4[q * 256 + tp] = g;
    }
    __syncthreads();
    // ---- B: d combine ----
    if (tid < 512) {
      int b = tid >> 8, h = tid & 255;
      ddp2[2 * h + b] = aA[(0 * 256 + h) * 2 + b] + aA[(1 * 256 + h) * 2 + b] +
                        aA[(2 * 256 + h) * 2 + b] + aA[(3 * 256 + h) * 2 + b] + bd1r;
    }
    __syncthreads();
    // ---- C: score partials (b0 LDS, b1 AGPR) ----
    {
      float q0 = 0.f, q1 = 0.f;
      const int rowbase = tp * 32, sw = tp & 31;
      CSTEP(0, ag00, ag01, ag02, ag03)
      CSTEP(1, ag04, ag05, ag06, ag07)
      CSTEP(2, ag08, ag09, ag10, ag11)
      CSTEP(3, ag12, ag13, ag14, ag15)
      CSTEP(4, ag16, ag17, ag18, ag19)
      CSTEP(5, ag20, ag21, ag22, ag23)
      CSTEP(6, ag24, ag25, ag26, ag27)
      CSTEP(7, ag28, ag29, ag30, ag31)
      aA[(q * 256 + tp) * 2 + 0] = q0;
      aA[(q * 256 + tp) * 2 + 1] = q1;
    }
    __syncthreads();
    // ---- D: softmax partial reductions (q<2, b=q; no max-shift) ----
    if (q < 2) {
      float v = aA[(0 * 256 + tp) * 2 + q] + aA[(1 * 256 + tp) * 2 + q] +
                aA[(2 * 256 + tp) * 2 + q] + aA[(3 * 256 + tp) * 2 + q] + bd2v;
      esc = __expf(v);
      float den = esc, num = esc * ewr;
      #pragma unroll
      for (int d = 1; d < 64; d <<= 1) { den += __shfl_xor(den, d); num += __shfl_xor(num, d); }
      if (lane == 0) { red[0][wvid] = den; red[1][wvid] = num; }
    }
    __syncthreads();
    // ---- F: y + gate combine + state update (tid<512, b=tid>>8) ----
    if (tid < 512) {
      int b = tid >> 8, jj = tid & 255;
      float den = red[0][b * 4 + 0] + red[0][b * 4 + 1] + red[0][b * 4 + 2] + red[0][b * 4 + 3];
      float num = red[1][b * 4 + 0] + red[1][b * 4 + 1] + red[1][b * 4 + 2] + red[1][b * 4 + 3];
      float inv = frcp(den);
      float y = num * inv + ybuf[2 * s + b];
      if (s == 254) invls = inv;
      float4 ga = gA4[(b * 2 + 0) * 256 + jj];
      float4 gb4 = gA4[(b * 2 + 1) * 256 + jj];
      float gi = ga.x + gb4.x + wy.x * y + biasd.x;
      float gf = ga.y + gb4.y + wy.y * y + biasd.y;
      float gg = ga.z + gb4.z + wy.z * y + biasd.z;
      float go = ga.w + gb4.w + wy.w * y + biasd.w;
      float c = fsig(gf) * creg + fsig(gi) * ftanh(gg);
      float h = fsig(go) * ftanh(c);
      creg = c; hreg = h;
      hcb[b][jj] = f2h(h);
      hcb[b][256 + jj] = f2h(c);
    }
    __syncthreads();
  }

  // ---- finale: last-step attention weights (alias over gA4) + ctx + output ----
  float* awls = (float*)gA4;
  if (q < 2) awls[2 * tp + q] = esc * invls;
  __syncthreads();
  {
    float c0 = 0.f, c1 = 0.f;
    const float* __restrict__ e0p = ws + OFF_ENC + (size_t)b0 * TT * HEE;
    const float* __restrict__ e1p = ws + OFF_ENC + (size_t)b1 * TT * HEE;
    for (int t = q * 64; t < q * 64 + 64; ++t) {
      float2 aw = *(const float2*)&awls[2 * t];
      c0 = fmaf(aw.x, e0p[(size_t)t * HEE + tp], c0);
      c1 = fmaf(aw.y, e1p[(size_t)t * HEE + tp], c1);
    }
    __syncthreads();
    aA[(q * 256 + tp) * 2 + 0] = c0;
    aA[(q * 256 + tp) * 2 + 1] = c1;
  }
  __syncthreads();
  if (tid < 512) {
    int b = tid >> 8, h = tid & 255;
    float ctx = aA[(0 * 256 + h) * 2 + b] + aA[(1 * 256 + h) * 2 + b] +
                aA[(2 * 256 + h) * 2 + b] + aA[(3 * 256 + h) * 2 + b];
    float p = hreg * wffh + ctx * wffc;
    #pragma unroll
    for (int d = 1; d < 64; d <<= 1) p += __shfl_xor(p, d);
    if (lane == 0) red[0][wvid] = p;
  }
  __syncthreads();
  if (tid == 0)   out[b0] = red[0][0] + red[0][1] + red[0][2] + red[0][3] + bffv;
  if (tid == 256) out[b1] = red[0][4] + red[0][5] + red[0][6] + red[0][7] + bffv;
}

extern "C" void kernel_launch(void* const* d_in, const int* in_sizes, int n_in,
                              void* d_out, int out_size, void* d_ws, size_t ws_size,
                              hipStream_t stream) {
  if (ws_size < (size_t)WS_FLOATS * sizeof(float)) return;
  const float* x     = (const float*)d_in[0];
  const float* y_h   = (const float*)d_in[1];
  const float* W_ah  = (const float*)d_in[2];
  const float* b_ah  = (const float*)d_in[3];
  const float* W_ai  = (const float*)d_in[4];
  const float* b_ai  = (const float*)d_in[5];
  const float* W_a   = (const float*)d_in[6];
  const float* b_a   = (const float*)d_in[7];
  const float* Wih_e = (const float*)d_in[8];
  const float* Whh_e = (const float*)d_in[9];
  const float* bih_e = (const float*)d_in[10];
  const float* bhh_e = (const float*)d_in[11];
  const float* W_d1  = (const float*)d_in[12];
  const float* b_d1  = (const float*)d_in[13];
  const float* W_d2  = (const float*)d_in[14];
  const float* b_d2  = (const float*)d_in[15];
  const float* W_fc  = (const float*)d_in[16];
  const float* b_fc  = (const float*)d_in[17];
  const float* Wih_d = (const float*)d_in[18];
  const float* Whh_d = (const float*)d_in[19];
  const float* bih_d = (const float*)d_in[20];
  const float* bhh_d = (const float*)d_in[21];
  const float* W_ff  = (const float*)d_in[22];
  const float* b_ff  = (const float*)d_in[23];
  float* ws  = (float*)d_ws;
  float* out = (float*)d_out;

  k_prep<<<256, 512, 0, stream>>>(W_ah, Wih_e, Whh_e, W_d1, Wih_d, Whh_d, ws);
  k_attn<<<512, 128, 0, stream>>>(x, W_ai, b_ai, ws);
  k_encoder<<<256, 1024, 0, stream>>>(x, b_ah, W_a, b_a, bih_e, bhh_e, ws);
  k_encw<<<1024, 256, 0, stream>>>(W_fc, ws);
  k_encproj<<<8192, 256, 0, stream>>>(W_d1, ws);
  k_decoder<<<256, 1024, 0, stream>>>(y_h, b_d1, W_d2, b_d2, W_fc, b_fc,
                                      Wih_d, bih_d, bhh_d, W_ff, b_ff, ws, out);
}